// Round 15
// baseline (382.165 us; speedup 1.0000x reference)
//
#include <hip/hip_runtime.h>
#include <math.h>

#define NQ     8
#define DIM    256
#define LAYERS 3
#define COUT   8
#define NB     32
#define OH     31
#define OW     31
#define NPATCH (NB*OH*OW)     // 30752
#define PT_BLK 512
#define NTILE  64             // 64 tiles x 8 ch = 512 blocks, XCD-bijective
#define PTOT   (NTILE*PT_BLK) // 32768
#define NPTILE (PTOT/16)      // 2048 16-patch groups
#define NPAIR  72             // packed upper-tri (t,ks) pairs
#define MPACK  (NPAIR*64*8)   // 36864 halves per channel
#define NWBLK  512            // W-part blocks (4 columns each, 1 wave/column)

typedef _Float16 f16x8 __attribute__((ext_vector_type(8)));
typedef _Float16 f16x4 __attribute__((ext_vector_type(4)));
typedef _Float16 f16x2 __attribute__((ext_vector_type(2)));
typedef __fp16   h16x2 __attribute__((ext_vector_type(2)));
typedef float    f32x4 __attribute__((ext_vector_type(4)));

__device__ __forceinline__ float2 cmul(float2 a, float2 b) {
    return make_float2(a.x*b.x - a.y*b.y, a.x*b.y + a.y*b.x);
}
__device__ __forceinline__ float2 cadd(float2 a, float2 b) {
    return make_float2(a.x + b.x, a.y + b.y);
}

__device__ __forceinline__ int rho(int i) {
    #pragma unroll
    for (int q = 7; q >= 0; --q) {
        int t = (q + 1) & 7;
        if ((i >> (7 - q)) & 1) i ^= 1 << (7 - t);
    }
    return i;
}

__device__ __forceinline__ void gload_lds16(const _Float16* g, _Float16* l) {
    __builtin_amdgcn_global_load_lds(
        (const __attribute__((address_space(1))) void*)g,
        (__attribute__((address_space(3))) void*)l, 16, 0, 0);
}

__device__ __forceinline__ float fold4(f16x4 sv, f32x4 a, float o) {
    h16x2 s01 = __builtin_bit_cast(h16x2, (f16x2)__builtin_shufflevector(sv, sv, 0, 1));
    h16x2 s23 = __builtin_bit_cast(h16x2, (f16x2)__builtin_shufflevector(sv, sv, 2, 3));
    h16x2 y01 = __builtin_amdgcn_cvt_pkrtz(a[0], a[1]);
    h16x2 y23 = __builtin_amdgcn_cvt_pkrtz(a[2], a[3]);
    o = __builtin_amdgcn_fdot2(s01, y01, o, false);
    o = __builtin_amdgcn_fdot2(s23, y23, o, false);
    return o;
}

__device__ __forceinline__ float dpp_ror_add(float x, int ctrl) {
    int xi = __builtin_bit_cast(int, x);
    int yi;
    switch (ctrl) {
        case 0x128: yi = __builtin_amdgcn_update_dpp(0, xi, 0x128, 0xf, 0xf, true); break;
        case 0x124: yi = __builtin_amdgcn_update_dpp(0, xi, 0x124, 0xf, 0xf, true); break;
        case 0x122: yi = __builtin_amdgcn_update_dpp(0, xi, 0x122, 0xf, 0xf, true); break;
        default:    yi = __builtin_amdgcn_update_dpp(0, xi, 0x121, 0xf, 0xf, true); break;
    }
    return x + __builtin_bit_cast(float, yi);
}

// ---- 1. merged dispatch (DIAGNOSTIC: body repeated `reps` times) -----------
__global__ __launch_bounds__(256) void wext(const float* __restrict__ w,
                                            _Float16* __restrict__ At,
                                            _Float16* __restrict__ Bt,
                                            const float* __restrict__ x,
                                            _Float16* __restrict__ sF,
                                            int reps) {
    __shared__ float2 g[96];
    __shared__ float2 vb[1024];
    __shared__ _Float16 sT[16][264];
    __shared__ float rsums[16][4];

    if (blockIdx.x < NWBLK) {
        const int ch  = blockIdx.x >> 6;
        const int wv  = threadIdx.x >> 6;
        const int l   = threadIdx.x & 63;
        const int col = (blockIdx.x & 63) * 4 + wv;

        if (threadIdx.x < 24) {
            const float* wp = w + (ch*24 + threadIdx.x)*3;
            float phi = wp[0], th = wp[1], om = wp[2];
            float cth = cosf(th * 0.5f), sth = sinf(th * 0.5f);
            float a = 0.5f * (phi + om), b = 0.5f * (phi - om);
            float sa, ca, sb, cb;
            sincosf(a, &sa, &ca);
            sincosf(b, &sb, &cb);
            g[threadIdx.x*4+0] = make_float2( cth*ca, -cth*sa);
            g[threadIdx.x*4+1] = make_float2(-sth*cb, -sth*sb);
            g[threadIdx.x*4+2] = make_float2( sth*cb, -sth*sb);
            g[threadIdx.x*4+3] = make_float2( cth*ca,  cth*sa);
        }
        __syncthreads();

        #pragma unroll 1
        for (int rep = 0; rep < reps; ++rep) {
            float2* vcol = vb + wv * 256;
            float2 v[4];
            #pragma unroll
            for (int k = 0; k < 4; ++k) {
                int r = l + 64*k;
                float2 acc = make_float2(1.f, 0.f);
                #pragma unroll
                for (int q = 0; q < 8; ++q) {
                    int iq = (r >> (7 - q)) & 1, jq = (col >> (7 - q)) & 1;
                    acc = cmul(acc, g[q*4 + iq*2 + jq]);
                }
                v[k] = acc;
            }

            #pragma unroll
            for (int lay = 1; lay < 3; ++lay) {
                #pragma unroll
                for (int k = 0; k < 4; ++k) vcol[l + 64*k] = v[k];
                #pragma unroll
                for (int k = 0; k < 4; ++k) v[k] = vcol[rho(l + 64*k)];
                {
                    const float2 g0 = g[(lay*8+0)*4+0], g1 = g[(lay*8+0)*4+1];
                    const float2 g2 = g[(lay*8+0)*4+2], g3 = g[(lay*8+0)*4+3];
                    float2 nv[4];
                    #pragma unroll
                    for (int k = 0; k < 4; ++k) {
                        float2 xx = v[k], yy = v[k^2];
                        nv[k] = (k & 2) ? cadd(cmul(g2, yy), cmul(g3, xx))
                                        : cadd(cmul(g0, xx), cmul(g1, yy));
                    }
                    #pragma unroll
                    for (int k = 0; k < 4; ++k) v[k] = nv[k];
                }
                {
                    const float2 g0 = g[(lay*8+1)*4+0], g1 = g[(lay*8+1)*4+1];
                    const float2 g2 = g[(lay*8+1)*4+2], g3 = g[(lay*8+1)*4+3];
                    float2 nv[4];
                    #pragma unroll
                    for (int k = 0; k < 4; ++k) {
                        float2 xx = v[k], yy = v[k^1];
                        nv[k] = (k & 1) ? cadd(cmul(g2, yy), cmul(g3, xx))
                                        : cadd(cmul(g0, xx), cmul(g1, yy));
                    }
                    #pragma unroll
                    for (int k = 0; k < 4; ++k) v[k] = nv[k];
                }
                #pragma unroll
                for (int q = 2; q < 8; ++q) {
                    int bit = 1 << (7 - q);
                    const float2 g0 = g[(lay*8+q)*4+0], g1 = g[(lay*8+q)*4+1];
                    const float2 g2 = g[(lay*8+q)*4+2], g3 = g[(lay*8+q)*4+3];
                    #pragma unroll
                    for (int k = 0; k < 4; ++k) {
                        float2 yy;
                        yy.x = __shfl_xor(v[k].x, bit, 64);
                        yy.y = __shfl_xor(v[k].y, bit, 64);
                        float2 m0 = (l & bit) ? g3 : g0;
                        float2 m1 = (l & bit) ? g2 : g1;
                        v[k] = cadd(cmul(m0, v[k]), cmul(m1, yy));
                    }
                }
            }
            #pragma unroll
            for (int k = 0; k < 4; ++k) vcol[l + 64*k] = v[k];
            #pragma unroll
            for (int k = 0; k < 4; ++k) v[k] = vcol[rho(l + 64*k)];

            size_t rowb = ((size_t)ch*256 + col) * 512;
            #pragma unroll
            for (int k = 0; k < 4; ++k) {
                int r = l + 64*k;
                float sgn = (r & 128) ? -1.f : 1.f;
                At[rowb + r]       = (_Float16)(sgn * v[k].x);
                At[rowb + 256 + r] = (_Float16)(sgn * v[k].y);
                Bt[rowb + r]       = (_Float16)v[k].x;
                Bt[rowb + 256 + r] = (_Float16)v[k].y;
            }
            __syncthreads();
        }
    } else {
        const int tb  = blockIdx.x - NWBLK;
        const int tid = threadIdx.x;
        const int wv  = tid >> 6, lane = tid & 63;

        #pragma unroll 1
        for (int rep = 0; rep < reps; ++rep) {
            float2 va[4], vc[4];
            #pragma unroll
            for (int pp = 0; pp < 4; ++pp) {
                int pl = wv*4 + pp;
                int p  = tb*16 + pl;
                float2 v01 = make_float2(0.f,0.f), v23 = make_float2(0.f,0.f);
                if (p < NPATCH) {
                    int b = p / (OH*OW); int r = p % (OH*OW);
                    int oi = r / OW, oj = r % OW;
                    int ci = lane >> 2, fi = lane & 3;
                    const float* xb = x + (((size_t)(b*16 + ci))*64 + (oi*2 + fi))*64 + oj*2;
                    v01 = *(const float2*)xb;
                    v23 = *(const float2*)(xb + 2);
                }
                va[pp] = v01; vc[pp] = v23;
                float ss = v01.x*v01.x + v01.y*v01.y + v23.x*v23.x + v23.y*v23.y;
                ss = dpp_ror_add(ss, 0x128);
                ss = dpp_ror_add(ss, 0x124);
                ss = dpp_ror_add(ss, 0x122);
                ss = dpp_ror_add(ss, 0x121);
                if ((lane & 15) == 0) rsums[pl][lane >> 4] = ss;
            }
            __syncthreads();

            #pragma unroll
            for (int pp = 0; pp < 4; ++pp) {
                int pl = wv*4 + pp;
                float tot = rsums[pl][0] + rsums[pl][1] + rsums[pl][2] + rsums[pl][3];
                float inv = tot > 0.f ? 1.f / sqrtf(tot) : 0.f;
                f16x4 o;
                o[0] = (_Float16)(va[pp].x*inv); o[1] = (_Float16)(va[pp].y*inv);
                o[2] = (_Float16)(vc[pp].x*inv); o[3] = (_Float16)(vc[pp].y*inv);
                *(f16x4*)&sT[pl][lane*4] = o;
            }
            __syncthreads();

            #pragma unroll
            for (int e = 0; e < 2; ++e) {
                int vi = tid + e*256;
                int ks = vi >> 6, ln = vi & 63;
                int kq = ln >> 4, prow = ln & 15;
                f16x8 o = *(const f16x8*)&sT[prow][ks*32 + kq*8];
                ((f16x8*)sF)[(size_t)tb*512 + vi] = o;
            }
            __syncthreads();
        }
    }
}

// ---- 2. build_Mp (DIAGNOSTIC: repeated) ------------------------------------
__global__ __launch_bounds__(256) void build_Mp(const _Float16* __restrict__ At,
                                                const _Float16* __restrict__ Bt,
                                                _Float16* __restrict__ Mp,
                                                int reps) {
    const int ch = blockIdx.z;
    const int ti = blockIdx.y;
    const int wv = threadIdx.x >> 6;
    const int jt = blockIdx.x * 4 + wv;
    const int jt0 = 2 * (ti >> 1);
    if (jt < jt0) return;
    const int lane = threadIdx.x & 63;
    const int c16 = lane & 15, kq = lane >> 4;
    const int h = ti >> 1;
    const int offt = 8*ti - (h*(h-1) + h*(ti & 1));
    const int pidx = offt + (jt >> 1) - h;
    _Float16* Mc = Mp + (size_t)ch * MPACK;

    #pragma unroll 1
    for (int rep = 0; rep < reps; ++rep) {
        f32x4 acc = {0.f, 0.f, 0.f, 0.f};
        if (jt >= ti) {
            const _Float16* Ar = At + ((size_t)ch*256 + ti*16 + c16) * 512 + kq*8;
            const _Float16* Br = Bt + ((size_t)ch*256 + jt*16 + c16) * 512 + kq*8;
            #pragma unroll
            for (int kk = 0; kk < 16; ++kk) {
                f16x8 af = *(const f16x8*)(Ar + kk*32);
                f16x8 bf = *(const f16x8*)(Br + kk*32);
                acc = __builtin_amdgcn_mfma_f32_16x16x32_f16(af, bf, acc, 0, 0, 0);
            }
        }
        int wsel = (jt & 1) * 16 + c16;
        int kqp = wsel >> 3, jj = wsel & 7;
        #pragma unroll
        for (int reg = 0; reg < 4; ++reg) {
            int i_g = ti*16 + kq*4 + reg;
            int j_g = jt*16 + c16;
            float val = (jt >= ti) ? acc[reg] : 0.f;
            val *= (j_g > i_g) ? 2.f : ((j_g == i_g) ? 1.f : 0.f);
            Mc[(size_t)((pidx*64 + kqp*16 + (kq*4 + reg)) * 8 + jj)] = (_Float16)val;
        }
    }
}

// ---- 3. fusedqf (DIAGNOSTIC: repeated) -------------------------------------
__global__ __attribute__((amdgpu_flat_work_group_size(512,512), amdgpu_waves_per_eu(2,4)))
void fusedqf(const _Float16* __restrict__ sF,
             const _Float16* __restrict__ Mp,
             const float* __restrict__ bias,
             float* __restrict__ out,
             int reps) {
    extern __shared__ _Float16 Mlds[];
    const int id   = blockIdx.x;
    const int xcd  = id & 7;
    const int g    = id >> 3;
    const int c    = g >> 3;
    const int tile = (g & 7) * 8 + xcd;
    const int tid  = threadIdx.x;
    const int lane = tid & 63;
    const int wv   = tid >> 6;
    const int prow = lane & 15, kq = lane >> 4;
    const int tp0  = tile*32 + wv*4;

    #pragma unroll 1
    for (int rep = 0; rep < reps; ++rep) {
        const _Float16* Msrc = Mp + (size_t)c * MPACK;
        #pragma unroll
        for (int it = 0; it < 9; ++it) {
            int off = (wv*9 + it) * 512;
            gload_lds16(Msrc + off + lane*8, Mlds + off);
        }

        f16x8 bfrag[4][4];
        #pragma unroll
        for (int pt = 0; pt < 4; ++pt) {
            const f16x8* src = (const f16x8*)sF + (size_t)(tp0 + pt)*512 + lane;
            #pragma unroll
            for (int ks = 0; ks < 4; ++ks)
                bfrag[pt][ks] = src[ks*64];
        }

        __syncthreads();

        const _Float16* fold0 = sF + ((size_t)tp0*512 + (kq>>1)*16 + prow)*8 + (kq&1)*4;
        float o0 = 0.f, o1 = 0.f, o2 = 0.f, o3 = 0.f;
        int pidx = 0;

        f16x4 svn[4];
        #pragma unroll
        for (int pt = 0; pt < 4; ++pt)
            svn[pt] = *(const f16x4*)(fold0 + pt*4096);

        #pragma unroll 1
        for (int t = 0; t < 8; ++t) {
            const int h = t >> 1;
            f16x4 svc[4];
            #pragma unroll
            for (int pt = 0; pt < 4; ++pt) svc[pt] = svn[pt];
            #pragma unroll
            for (int pt = 0; pt < 4; ++pt)
                svn[pt] = *(const f16x4*)(fold0 + pt*4096 + (t+1)*256);

            f32x4 a0 = {0,0,0,0}, a1 = {0,0,0,0}, a2 = {0,0,0,0}, a3 = {0,0,0,0};
            __builtin_amdgcn_s_setprio(1);
            #pragma unroll
            for (int ks = 0; ks < 4; ++ks) {
                if (ks >= h) {
                    f16x8 m = *(const f16x8*)(Mlds + (size_t)pidx*512 + lane*8);
                    a0 = __builtin_amdgcn_mfma_f32_16x16x32_f16(m, bfrag[0][ks], a0, 0, 0, 0);
                    a1 = __builtin_amdgcn_mfma_f32_16x16x32_f16(m, bfrag[1][ks], a1, 0, 0, 0);
                    a2 = __builtin_amdgcn_mfma_f32_16x16x32_f16(m, bfrag[2][ks], a2, 0, 0, 0);
                    a3 = __builtin_amdgcn_mfma_f32_16x16x32_f16(m, bfrag[3][ks], a3, 0, 0, 0);
                    ++pidx;
                }
            }
            __builtin_amdgcn_s_setprio(0);
            pidx += 4;

            o0 = fold4(svc[0], a0, o0);
            o1 = fold4(svc[1], a1, o1);
            o2 = fold4(svc[2], a2, o2);
            o3 = fold4(svc[3], a3, o3);
        }

        #pragma unroll
        for (int pt = 0; pt < 4; ++pt) {
            const f16x8* src = (const f16x8*)sF + (size_t)(tp0 + pt)*512 + lane;
            #pragma unroll
            for (int ks = 0; ks < 4; ++ks)
                bfrag[pt][ks] = src[(ks+4)*64];
        }

        pidx = 0;
        #pragma unroll
        for (int pt = 0; pt < 4; ++pt)
            svn[pt] = *(const f16x4*)(fold0 + pt*4096);

        #pragma unroll 1
        for (int t = 0; t < 16; ++t) {
            const int h = t >> 1;
            pidx += (h < 4) ? (4 - h) : 0;
            f16x4 svc[4];
            #pragma unroll
            for (int pt = 0; pt < 4; ++pt) svc[pt] = svn[pt];
            if (t < 15) {
                #pragma unroll
                for (int pt = 0; pt < 4; ++pt)
                    svn[pt] = *(const f16x4*)(fold0 + pt*4096 + (t+1)*256);
            }

            f32x4 a0 = {0,0,0,0}, a1 = {0,0,0,0}, a2 = {0,0,0,0}, a3 = {0,0,0,0};
            __builtin_amdgcn_s_setprio(1);
            #pragma unroll
            for (int ks = 4; ks < 8; ++ks) {
                if (ks >= h) {
                    f16x8 m = *(const f16x8*)(Mlds + (size_t)pidx*512 + lane*8);
                    a0 = __builtin_amdgcn_mfma_f32_16x16x32_f16(m, bfrag[0][ks-4], a0, 0, 0, 0);
                    a1 = __builtin_amdgcn_mfma_f32_16x16x32_f16(m, bfrag[1][ks-4], a1, 0, 0, 0);
                    a2 = __builtin_amdgcn_mfma_f32_16x16x32_f16(m, bfrag[2][ks-4], a2, 0, 0, 0);
                    a3 = __builtin_amdgcn_mfma_f32_16x16x32_f16(m, bfrag[3][ks-4], a3, 0, 0, 0);
                    ++pidx;
                }
            }
            __builtin_amdgcn_s_setprio(0);

            o0 = fold4(svc[0], a0, o0);
            o1 = fold4(svc[1], a1, o1);
            o2 = fold4(svc[2], a2, o2);
            o3 = fold4(svc[3], a3, o3);
        }

        float ov[4] = {o0, o1, o2, o3};
        float bc = bias[c];
        #pragma unroll
        for (int pt = 0; pt < 4; ++pt) {
            float v = ov[pt];
            v += __shfl_xor(v, 16, 64);
            v += __shfl_xor(v, 32, 64);
            if (kq == 0) {
                int p = (tp0 + pt)*16 + prow;
                if (p < NPATCH) {
                    int b = p / (OH*OW); int r2 = p % (OH*OW);
                    int oi = r2 / OW, oj = r2 % OW;
                    out[(((size_t)(b*COUT + c))*OH + oi)*OW + oj] = v + bc;
                }
            }
        }
        __syncthreads();   // Mlds re-staged next rep
    }
}

extern "C" void kernel_launch(void* const* d_in, const int* in_sizes, int n_in,
                              void* d_out, int out_size, void* d_ws, size_t ws_size,
                              hipStream_t stream) {
    const float* x    = (const float*)d_in[0];
    const float* w    = (const float*)d_in[1];
    const float* bias = (const float*)d_in[2];
    float* out = (float*)d_out;

    const size_t OFF_AT  = 0;
    const size_t OFF_BT  = OFF_AT + 2097152;
    const size_t OFF_MP  = OFF_BT + 2097152;
    const size_t OFF_SF  = OFF_MP + 589824;
    const size_t TOTAL   = OFF_SF + 16777216;
    if (ws_size < TOTAL) return;

    char* ws = (char*)d_ws;
    _Float16* At = (_Float16*)(ws + OFF_AT);
    _Float16* Bt = (_Float16*)(ws + OFF_BT);
    _Float16* Mp = (_Float16*)(ws + OFF_MP);
    _Float16* sF = (_Float16*)(ws + OFF_SF);

    // DIAGNOSTIC ROUND: internal body repeats lift each kernel above the 41us
    // fill dispatches so rocprof top-5 yields per-kernel durations (/R).
    wext<<<NWBLK + NPTILE, 256, 0, stream>>>(w, At, Bt, x, sF, 8);
    build_Mp<<<dim3(4, 16, COUT), 256, 0, stream>>>(At, Bt, Mp, 32);
    fusedqf<<<NTILE*COUT, 512, MPACK*sizeof(_Float16), stream>>>(sF, Mp, bias, out, 4);
}

// Round 16
// 52.458 us; speedup vs baseline: 7.2851x; 7.2851x over previous
//
#include <hip/hip_runtime.h>
#include <math.h>

#define NQ     8
#define DIM    256
#define LAYERS 3
#define COUT   8
#define NB     32
#define OH     31
#define OW     31
#define NPATCH (NB*OH*OW)     // 30752
#define PT_BLK 512
#define NTILE  64             // 64 tiles x 8 ch = 512 blocks, XCD-bijective
#define PTOT   (NTILE*PT_BLK) // 32768
#define NPTILE (PTOT/16)      // 2048 16-patch groups
#define NPAIR  72             // packed upper-tri (t,ks) pairs
#define MPACK  (NPAIR*64*8)   // 36864 halves per channel
#define NWBLK  512            // W-part blocks (4 columns each, 1 wave/column)

typedef _Float16 f16x8 __attribute__((ext_vector_type(8)));
typedef _Float16 f16x4 __attribute__((ext_vector_type(4)));
typedef _Float16 f16x2 __attribute__((ext_vector_type(2)));
typedef __fp16   h16x2 __attribute__((ext_vector_type(2)));
typedef float    f32x4 __attribute__((ext_vector_type(4)));

// packed-pair decode tables (p -> ti, and OFFT for jp recovery)
__device__ __constant__ unsigned char TI_OF_P[NPAIR] = {
    0,0,0,0,0,0,0,0, 1,1,1,1,1,1,1,1, 2,2,2,2,2,2,2, 3,3,3,3,3,3,3,
    4,4,4,4,4,4, 5,5,5,5,5,5, 6,6,6,6,6, 7,7,7,7,7, 8,8,8,8, 9,9,9,9,
    10,10,10, 11,11,11, 12,12, 13,13, 14, 15};
__device__ __constant__ unsigned char OFFT_C[16] =
    {0,8,16,23,30,36,42,47,52,56,60,63,66,68,70,71};

__device__ __forceinline__ float2 cmul(float2 a, float2 b) {
    return make_float2(a.x*b.x - a.y*b.y, a.x*b.y + a.y*b.x);
}
__device__ __forceinline__ float2 cadd(float2 a, float2 b) {
    return make_float2(a.x + b.x, a.y + b.y);
}

__device__ __forceinline__ int rho(int i) {
    #pragma unroll
    for (int q = 7; q >= 0; --q) {
        int t = (q + 1) & 7;
        if ((i >> (7 - q)) & 1) i ^= 1 << (7 - t);
    }
    return i;
}

__device__ __forceinline__ void gload_lds16(const _Float16* g, _Float16* l) {
    __builtin_amdgcn_global_load_lds(
        (const __attribute__((address_space(1))) void*)g,
        (__attribute__((address_space(3))) void*)l, 16, 0, 0);
}

__device__ __forceinline__ float fold4(f16x4 sv, f32x4 a, float o) {
    h16x2 s01 = __builtin_bit_cast(h16x2, (f16x2)__builtin_shufflevector(sv, sv, 0, 1));
    h16x2 s23 = __builtin_bit_cast(h16x2, (f16x2)__builtin_shufflevector(sv, sv, 2, 3));
    h16x2 y01 = __builtin_amdgcn_cvt_pkrtz(a[0], a[1]);
    h16x2 y23 = __builtin_amdgcn_cvt_pkrtz(a[2], a[3]);
    o = __builtin_amdgcn_fdot2(s01, y01, o, false);
    o = __builtin_amdgcn_fdot2(s23, y23, o, false);
    return o;
}

__device__ __forceinline__ float dpp_ror_add(float x, int ctrl) {
    int xi = __builtin_bit_cast(int, x);
    int yi;
    switch (ctrl) {
        case 0x128: yi = __builtin_amdgcn_update_dpp(0, xi, 0x128, 0xf, 0xf, true); break;
        case 0x124: yi = __builtin_amdgcn_update_dpp(0, xi, 0x124, 0xf, 0xf, true); break;
        case 0x122: yi = __builtin_amdgcn_update_dpp(0, xi, 0x122, 0xf, 0xf, true); break;
        default:    yi = __builtin_amdgcn_update_dpp(0, xi, 0x121, 0xf, 0xf, true); break;
    }
    return x + __builtin_bit_cast(float, yi);
}

// ---- 1. merged dispatch: blocks [0,512) build W, [512, 512+2048) extract ---
__global__ __launch_bounds__(256) void wext(const float* __restrict__ w,
                                            _Float16* __restrict__ At,
                                            _Float16* __restrict__ Bt,
                                            const float* __restrict__ x,
                                            _Float16* __restrict__ sF) {
    __shared__ float2 g[96];
    __shared__ float2 vb[1024];
    __shared__ _Float16 sT[16][264];
    __shared__ float rsums[16][4];

    if (blockIdx.x < NWBLK) {
        const int ch  = blockIdx.x >> 6;
        const int wv  = threadIdx.x >> 6;
        const int l   = threadIdx.x & 63;
        const int col = (blockIdx.x & 63) * 4 + wv;

        if (threadIdx.x < 24) {
            const float* wp = w + (ch*24 + threadIdx.x)*3;
            float phi = wp[0], th = wp[1], om = wp[2];
            float cth = cosf(th * 0.5f), sth = sinf(th * 0.5f);
            float a = 0.5f * (phi + om), b = 0.5f * (phi - om);
            float sa, ca, sb, cb;
            sincosf(a, &sa, &ca);
            sincosf(b, &sb, &cb);
            g[threadIdx.x*4+0] = make_float2( cth*ca, -cth*sa);
            g[threadIdx.x*4+1] = make_float2(-sth*cb, -sth*sb);
            g[threadIdx.x*4+2] = make_float2( sth*cb, -sth*sb);
            g[threadIdx.x*4+3] = make_float2( cth*ca,  cth*sa);
        }
        __syncthreads();

        float2* vcol = vb + wv * 256;
        float2 v[4];
        #pragma unroll
        for (int k = 0; k < 4; ++k) {
            int r = l + 64*k;
            float2 acc = make_float2(1.f, 0.f);
            #pragma unroll
            for (int q = 0; q < 8; ++q) {
                int iq = (r >> (7 - q)) & 1, jq = (col >> (7 - q)) & 1;
                acc = cmul(acc, g[q*4 + iq*2 + jq]);
            }
            v[k] = acc;
        }

        #pragma unroll
        for (int lay = 1; lay < 3; ++lay) {
            #pragma unroll
            for (int k = 0; k < 4; ++k) vcol[l + 64*k] = v[k];
            #pragma unroll
            for (int k = 0; k < 4; ++k) v[k] = vcol[rho(l + 64*k)];
            {
                const float2 g0 = g[(lay*8+0)*4+0], g1 = g[(lay*8+0)*4+1];
                const float2 g2 = g[(lay*8+0)*4+2], g3 = g[(lay*8+0)*4+3];
                float2 nv[4];
                #pragma unroll
                for (int k = 0; k < 4; ++k) {
                    float2 xx = v[k], yy = v[k^2];
                    nv[k] = (k & 2) ? cadd(cmul(g2, yy), cmul(g3, xx))
                                    : cadd(cmul(g0, xx), cmul(g1, yy));
                }
                #pragma unroll
                for (int k = 0; k < 4; ++k) v[k] = nv[k];
            }
            {
                const float2 g0 = g[(lay*8+1)*4+0], g1 = g[(lay*8+1)*4+1];
                const float2 g2 = g[(lay*8+1)*4+2], g3 = g[(lay*8+1)*4+3];
                float2 nv[4];
                #pragma unroll
                for (int k = 0; k < 4; ++k) {
                    float2 xx = v[k], yy = v[k^1];
                    nv[k] = (k & 1) ? cadd(cmul(g2, yy), cmul(g3, xx))
                                    : cadd(cmul(g0, xx), cmul(g1, yy));
                }
                #pragma unroll
                for (int k = 0; k < 4; ++k) v[k] = nv[k];
            }
            #pragma unroll
            for (int q = 2; q < 8; ++q) {
                int bit = 1 << (7 - q);
                const float2 g0 = g[(lay*8+q)*4+0], g1 = g[(lay*8+q)*4+1];
                const float2 g2 = g[(lay*8+q)*4+2], g3 = g[(lay*8+q)*4+3];
                #pragma unroll
                for (int k = 0; k < 4; ++k) {
                    float2 yy;
                    yy.x = __shfl_xor(v[k].x, bit, 64);
                    yy.y = __shfl_xor(v[k].y, bit, 64);
                    float2 m0 = (l & bit) ? g3 : g0;
                    float2 m1 = (l & bit) ? g2 : g1;
                    v[k] = cadd(cmul(m0, v[k]), cmul(m1, yy));
                }
            }
        }
        #pragma unroll
        for (int k = 0; k < 4; ++k) vcol[l + 64*k] = v[k];
        #pragma unroll
        for (int k = 0; k < 4; ++k) v[k] = vcol[rho(l + 64*k)];

        size_t rowb = ((size_t)ch*256 + col) * 512;
        #pragma unroll
        for (int k = 0; k < 4; ++k) {
            int r = l + 64*k;
            float sgn = (r & 128) ? -1.f : 1.f;
            At[rowb + r]       = (_Float16)(sgn * v[k].x);
            At[rowb + 256 + r] = (_Float16)(sgn * v[k].y);
            Bt[rowb + r]       = (_Float16)v[k].x;
            Bt[rowb + 256 + r] = (_Float16)v[k].y;
        }
    } else {
        const int tb  = blockIdx.x - NWBLK;
        const int tid = threadIdx.x;
        const int wv  = tid >> 6, lane = tid & 63;

        float2 va[4], vc[4];
        #pragma unroll
        for (int pp = 0; pp < 4; ++pp) {
            int pl = wv*4 + pp;
            int p  = tb*16 + pl;
            float2 v01 = make_float2(0.f,0.f), v23 = make_float2(0.f,0.f);
            if (p < NPATCH) {
                int b = p / (OH*OW); int r = p % (OH*OW);
                int oi = r / OW, oj = r % OW;
                int ci = lane >> 2, fi = lane & 3;
                const float* xb = x + (((size_t)(b*16 + ci))*64 + (oi*2 + fi))*64 + oj*2;
                v01 = *(const float2*)xb;
                v23 = *(const float2*)(xb + 2);
            }
            va[pp] = v01; vc[pp] = v23;
            float ss = v01.x*v01.x + v01.y*v01.y + v23.x*v23.x + v23.y*v23.y;
            ss = dpp_ror_add(ss, 0x128);
            ss = dpp_ror_add(ss, 0x124);
            ss = dpp_ror_add(ss, 0x122);
            ss = dpp_ror_add(ss, 0x121);
            if ((lane & 15) == 0) rsums[pl][lane >> 4] = ss;
        }
        __syncthreads();

        #pragma unroll
        for (int pp = 0; pp < 4; ++pp) {
            int pl = wv*4 + pp;
            float tot = rsums[pl][0] + rsums[pl][1] + rsums[pl][2] + rsums[pl][3];
            float inv = tot > 0.f ? 1.f / sqrtf(tot) : 0.f;
            f16x4 o;
            o[0] = (_Float16)(va[pp].x*inv); o[1] = (_Float16)(va[pp].y*inv);
            o[2] = (_Float16)(vc[pp].x*inv); o[3] = (_Float16)(vc[pp].y*inv);
            *(f16x4*)&sT[pl][lane*4] = o;
        }
        __syncthreads();

        #pragma unroll
        for (int e = 0; e < 2; ++e) {
            int vi = tid + e*256;
            int ks = vi >> 6, ln = vi & 63;
            int kq = ln >> 4, prow = ln & 15;
            f16x8 o = *(const f16x8*)&sT[prow][ks*32 + kq*8];
            ((f16x8*)sF)[(size_t)tb*512 + vi] = o;
        }
    }
}

// ---- 2. M' build, RESTRUCTURED (r15 diag: was 7.1us, latency-serialized) ---
// 288 blocks x 4 waves = 1152 waves, one per (ch, pair, odd) -- no idle waves.
// All 16 K-step operand pairs loaded up-front (one L2 latency, ~128 VGPR of
// loads enabled by waves_per_eu(1,4)), then 4 independent MFMA acc chains.
__global__ __launch_bounds__(256) __attribute__((amdgpu_waves_per_eu(1,4)))
void build_Mp(const _Float16* __restrict__ At,
              const _Float16* __restrict__ Bt,
              _Float16* __restrict__ Mp) {
    const int wv   = threadIdx.x >> 6;
    const int lane = threadIdx.x & 63;
    const int s    = blockIdx.x * 4 + wv;      // 0..1151
    const int ch   = s / 144;
    const int r    = s % 144;
    const int p    = r >> 1;                   // packed pair index 0..71
    const int odd  = r & 1;
    const int ti   = TI_OF_P[p];
    const int jp   = p - OFFT_C[ti] + (ti >> 1);
    const int jt   = jp*2 + odd;
    const int c16  = lane & 15, kq = lane >> 4;
    _Float16* Mc = Mp + (size_t)ch * MPACK;

    f32x4 a0 = {0,0,0,0}, a1 = {0,0,0,0}, a2 = {0,0,0,0}, a3 = {0,0,0,0};
    if (jt >= ti) {
        const _Float16* Ar = At + ((size_t)ch*256 + ti*16 + c16) * 512 + kq*8;
        const _Float16* Br = Bt + ((size_t)ch*256 + jt*16 + c16) * 512 + kq*8;
        f16x8 af[16], bf[16];
        #pragma unroll
        for (int kk = 0; kk < 16; ++kk) {
            af[kk] = *(const f16x8*)(Ar + kk*32);
            bf[kk] = *(const f16x8*)(Br + kk*32);
        }
        #pragma unroll
        for (int kk = 0; kk < 16; kk += 4) {
            a0 = __builtin_amdgcn_mfma_f32_16x16x32_f16(af[kk+0], bf[kk+0], a0, 0, 0, 0);
            a1 = __builtin_amdgcn_mfma_f32_16x16x32_f16(af[kk+1], bf[kk+1], a1, 0, 0, 0);
            a2 = __builtin_amdgcn_mfma_f32_16x16x32_f16(af[kk+2], bf[kk+2], a2, 0, 0, 0);
            a3 = __builtin_amdgcn_mfma_f32_16x16x32_f16(af[kk+3], bf[kk+3], a3, 0, 0, 0);
        }
        a0 = a0 + a1 + a2 + a3;
    }

    const int wsel = odd * 16 + c16;
    const int kqp = wsel >> 3, jj = wsel & 7;
    #pragma unroll
    for (int reg = 0; reg < 4; ++reg) {
        int i_g = ti*16 + kq*4 + reg;
        int j_g = jt*16 + c16;
        float val = (jt >= ti) ? a0[reg] : 0.f;
        val *= (j_g > i_g) ? 2.f : ((j_g == i_g) ? 1.f : 0.f);
        Mc[(size_t)((p*64 + kqp*16 + (kq*4 + reg)) * 8 + jj)] = (_Float16)val;
    }
}

// ---- 3. fused MFMA quadform (BYTE-IDENTICAL to r14) -------------------------
__global__ __attribute__((amdgpu_flat_work_group_size(512,512), amdgpu_waves_per_eu(2,4)))
void fusedqf(const _Float16* __restrict__ sF,
             const _Float16* __restrict__ Mp,
             const float* __restrict__ bias,
             float* __restrict__ out) {
    extern __shared__ _Float16 Mlds[];
    const int id   = blockIdx.x;
    const int xcd  = id & 7;
    const int g    = id >> 3;
    const int c    = g >> 3;
    const int tile = (g & 7) * 8 + xcd;
    const int tid  = threadIdx.x;
    const int lane = tid & 63;
    const int wv   = tid >> 6;
    const int prow = lane & 15, kq = lane >> 4;
    const int tp0  = tile*32 + wv*4;

    const _Float16* Msrc = Mp + (size_t)c * MPACK;
    #pragma unroll
    for (int it = 0; it < 9; ++it) {
        int off = (wv*9 + it) * 512;
        gload_lds16(Msrc + off + lane*8, Mlds + off);
    }

    f16x8 bfrag[4][4];
    #pragma unroll
    for (int pt = 0; pt < 4; ++pt) {
        const f16x8* src = (const f16x8*)sF + (size_t)(tp0 + pt)*512 + lane;
        #pragma unroll
        for (int ks = 0; ks < 4; ++ks)
            bfrag[pt][ks] = src[ks*64];
    }

    __syncthreads();

    const _Float16* fold0 = sF + ((size_t)tp0*512 + (kq>>1)*16 + prow)*8 + (kq&1)*4;
    float o0 = 0.f, o1 = 0.f, o2 = 0.f, o3 = 0.f;
    int pidx = 0;

    f16x4 svn[4];
    #pragma unroll
    for (int pt = 0; pt < 4; ++pt)
        svn[pt] = *(const f16x4*)(fold0 + pt*4096);

    #pragma unroll 1
    for (int t = 0; t < 8; ++t) {
        const int h = t >> 1;
        f16x4 svc[4];
        #pragma unroll
        for (int pt = 0; pt < 4; ++pt) svc[pt] = svn[pt];
        #pragma unroll
        for (int pt = 0; pt < 4; ++pt)
            svn[pt] = *(const f16x4*)(fold0 + pt*4096 + (t+1)*256);

        f32x4 a0 = {0,0,0,0}, a1 = {0,0,0,0}, a2 = {0,0,0,0}, a3 = {0,0,0,0};
        __builtin_amdgcn_s_setprio(1);
        #pragma unroll
        for (int ks = 0; ks < 4; ++ks) {
            if (ks >= h) {
                f16x8 m = *(const f16x8*)(Mlds + (size_t)pidx*512 + lane*8);
                a0 = __builtin_amdgcn_mfma_f32_16x16x32_f16(m, bfrag[0][ks], a0, 0, 0, 0);
                a1 = __builtin_amdgcn_mfma_f32_16x16x32_f16(m, bfrag[1][ks], a1, 0, 0, 0);
                a2 = __builtin_amdgcn_mfma_f32_16x16x32_f16(m, bfrag[2][ks], a2, 0, 0, 0);
                a3 = __builtin_amdgcn_mfma_f32_16x16x32_f16(m, bfrag[3][ks], a3, 0, 0, 0);
                ++pidx;
            }
        }
        __builtin_amdgcn_s_setprio(0);
        pidx += 4;

        o0 = fold4(svc[0], a0, o0);
        o1 = fold4(svc[1], a1, o1);
        o2 = fold4(svc[2], a2, o2);
        o3 = fold4(svc[3], a3, o3);
    }

    #pragma unroll
    for (int pt = 0; pt < 4; ++pt) {
        const f16x8* src = (const f16x8*)sF + (size_t)(tp0 + pt)*512 + lane;
        #pragma unroll
        for (int ks = 0; ks < 4; ++ks)
            bfrag[pt][ks] = src[(ks+4)*64];
    }

    pidx = 0;
    #pragma unroll
    for (int pt = 0; pt < 4; ++pt)
        svn[pt] = *(const f16x4*)(fold0 + pt*4096);

    #pragma unroll 1
    for (int t = 0; t < 16; ++t) {
        const int h = t >> 1;
        pidx += (h < 4) ? (4 - h) : 0;
        f16x4 svc[4];
        #pragma unroll
        for (int pt = 0; pt < 4; ++pt) svc[pt] = svn[pt];
        if (t < 15) {
            #pragma unroll
            for (int pt = 0; pt < 4; ++pt)
                svn[pt] = *(const f16x4*)(fold0 + pt*4096 + (t+1)*256);
        }

        f32x4 a0 = {0,0,0,0}, a1 = {0,0,0,0}, a2 = {0,0,0,0}, a3 = {0,0,0,0};
        __builtin_amdgcn_s_setprio(1);
        #pragma unroll
        for (int ks = 4; ks < 8; ++ks) {
            if (ks >= h) {
                f16x8 m = *(const f16x8*)(Mlds + (size_t)pidx*512 + lane*8);
                a0 = __builtin_amdgcn_mfma_f32_16x16x32_f16(m, bfrag[0][ks-4], a0, 0, 0, 0);
                a1 = __builtin_amdgcn_mfma_f32_16x16x32_f16(m, bfrag[1][ks-4], a1, 0, 0, 0);
                a2 = __builtin_amdgcn_mfma_f32_16x16x32_f16(m, bfrag[2][ks-4], a2, 0, 0, 0);
                a3 = __builtin_amdgcn_mfma_f32_16x16x32_f16(m, bfrag[3][ks-4], a3, 0, 0, 0);
                ++pidx;
            }
        }
        __builtin_amdgcn_s_setprio(0);

        o0 = fold4(svc[0], a0, o0);
        o1 = fold4(svc[1], a1, o1);
        o2 = fold4(svc[2], a2, o2);
        o3 = fold4(svc[3], a3, o3);
    }

    float ov[4] = {o0, o1, o2, o3};
    float bc = bias[c];
    #pragma unroll
    for (int pt = 0; pt < 4; ++pt) {
        float v = ov[pt];
        v += __shfl_xor(v, 16, 64);
        v += __shfl_xor(v, 32, 64);
        if (kq == 0) {
            int p = (tp0 + pt)*16 + prow;
            if (p < NPATCH) {
                int b = p / (OH*OW); int r2 = p % (OH*OW);
                int oi = r2 / OW, oj = r2 % OW;
                out[(((size_t)(b*COUT + c))*OH + oi)*OW + oj] = v + bc;
            }
        }
    }
}

extern "C" void kernel_launch(void* const* d_in, const int* in_sizes, int n_in,
                              void* d_out, int out_size, void* d_ws, size_t ws_size,
                              hipStream_t stream) {
    const float* x    = (const float*)d_in[0];
    const float* w    = (const float*)d_in[1];
    const float* bias = (const float*)d_in[2];
    float* out = (float*)d_out;

    const size_t OFF_AT  = 0;
    const size_t OFF_BT  = OFF_AT + 2097152;
    const size_t OFF_MP  = OFF_BT + 2097152;
    const size_t OFF_SF  = OFF_MP + 589824;
    const size_t TOTAL   = OFF_SF + 16777216;
    if (ws_size < TOTAL) return;

    char* ws = (char*)d_ws;
    _Float16* At = (_Float16*)(ws + OFF_AT);
    _Float16* Bt = (_Float16*)(ws + OFF_BT);
    _Float16* Mp = (_Float16*)(ws + OFF_MP);
    _Float16* sF = (_Float16*)(ws + OFF_SF);

    wext<<<NWBLK + NPTILE, 256, 0, stream>>>(w, At, Bt, x, sF);
    build_Mp<<<288, 256, 0, stream>>>(At, Bt, Mp);
    fusedqf<<<NTILE*COUT, 512, MPACK*sizeof(_Float16), stream>>>(sF, Mp, bias, out);
}